// Round 13
// baseline (68.668 us; speedup 1.0000x reference)
//
#include <hip/hip_runtime.h>

#define B_    8
#define C_    64
#define O_    64
#define H_    128
#define W_    128
#define HW_   (H_ * W_)
#define NOFF_ 18
#define KK_   9
#define TW_   19       // staged tile span (8 + 2*5 + 1)
#define PADW_ 5
#define RSTR_ 144      // LDS row stride in bytes (non-pow2)

typedef __attribute__((ext_vector_type(8))) _Float16 f16x8;
typedef __attribute__((ext_vector_type(2))) _Float16 f16x2;
typedef __attribute__((ext_vector_type(4))) unsigned int u32x4;
typedef __attribute__((ext_vector_type(4))) float f32x4;
typedef unsigned int uint32;
typedef unsigned short ushort;

__device__ __forceinline__ f16x2 u2h(uint32 u) {
    union { uint32 u; f16x2 h; } c; c.u = u; return c.h;
}
__device__ __forceinline__ f16x8 u2h8(u32x4 q) {
    union { u32x4 u; f16x8 h; } c; c.u = q; return c.h;
}

#define GLOAD16(dst, a64) \
    asm volatile("global_load_dwordx4 %0, %1, off" : "=&v"(dst) : "v"(a64) : "memory")
#define WAITV_TIE(N, w) \
    asm volatile("s_waitcnt vmcnt(" #N ")" \
        : "+v"(w[0]), "+v"(w[1]), "+v"(w[2]), "+v"(w[3]), \
          "+v"(w[4]), "+v"(w[5]), "+v"(w[6]), "+v"(w[7]))
#define WAITV(N) do { \
    asm volatile("s_waitcnt vmcnt(" #N ")" ::: "memory"); \
    __builtin_amdgcn_sched_barrier(0); } while (0)
#define DRAIN_ALL() do { \
    asm volatile("s_waitcnt vmcnt(0) lgkmcnt(0)" ::: "memory"); \
    __builtin_amdgcn_sched_barrier(0); } while (0)

// ---------------------------------------------------------------------------
// x [b][c][hw] f32  ->  xT [b][hw][c] f16   (LDS tile transpose)
// ---------------------------------------------------------------------------
__global__ __launch_bounds__(256) void transpose_x(
    const float* __restrict__ x, _Float16* __restrict__ xT)
{
    __shared__ float tile[64][65];
    int blk = blockIdx.x;
    int b   = blk >> 8;
    int hw0 = (blk & 255) * 64;
    int t   = threadIdx.x;
    int q   = t >> 6;
    int ln  = t & 63;
#pragma unroll
    for (int p = 0; p < 16; ++p) {
        int c = p * 4 + q;
        tile[c][ln] = x[((size_t)(b * C_ + c) << 14) + hw0 + ln];
    }
    __syncthreads();
#pragma unroll
    for (int p = 0; p < 16; ++p) {
        int hw = p * 4 + q;
        xT[(((size_t)b << 14) + hw0 + hw) * 64 + ln] = (_Float16)tile[ln][hw];
    }
}

// ---------------------------------------------------------------------------
// Weight fragments (f16).
// ---------------------------------------------------------------------------
__global__ __launch_bounds__(256) void prep3(
    const float* __restrict__ w_conv, const float* __restrict__ w_off,
    _Float16* __restrict__ wfrag, _Float16* __restrict__ wofff)
{
    int idx = blockIdx.x * 256 + threadIdx.x;
    if (idx < 36864) {
        int i    = idx & 7;
        int lane = (idx >> 3) & 63;
        int nb   = (idx >> 9) & 3;
        int kc   = (idx >> 11) & 1;
        int kk   = idx >> 12;
        int c = kc * 32 + ((lane >> 4) << 3) + i;
        int o = nb * 16 + (lane & 15);
        wfrag[idx] = (_Float16)w_conv[(o * C_ + c) * 9 + kk];
    }
    if (idx < 18432) {
        int i    = idx & 7;
        int lane = (idx >> 3) & 63;
        int nb   = (idx >> 9) & 1;
        int kc   = (idx >> 10) & 1;
        int kk   = idx >> 11;
        int m = nb * 16 + (lane & 15);
        int c = kc * 32 + ((lane >> 4) << 3) + i;
        wofff[idx] = (_Float16)((m < NOFF_) ? w_off[(m * C_ + c) * 9 + kk] : 0.0f);
    }
}

// ---------------------------------------------------------------------------
// Offset conv (R7-proven, unchanged).
// ---------------------------------------------------------------------------
__global__ __launch_bounds__(512, 2) void offconv_mfma5(
    const _Float16* __restrict__ xT, const _Float16* __restrict__ wofff,
    const float* __restrict__ b_off, _Float16* __restrict__ offsh)
{
    __shared__ _Float16 wlds[18432];
    int t = threadIdx.x;
    {
        const u32x4* src = (const u32x4*)wofff;
        u32x4* dst = (u32x4*)wlds;
#pragma unroll
        for (int r = 0; r < 5; ++r) {
            int i = r * 512 + t;
            if (i < 2304) dst[i] = src[i];
        }
    }
    DRAIN_ALL();
    __syncthreads();

    int blk  = blockIdx.x;
    int b    = blk & 7;
    int hw0  = (blk >> 3) * 128;
    int lane = t & 63;
    int wv   = t >> 6;
    int pxb  = hw0 + wv * 16;
    int pr   = lane & 15;
    int g    = lane >> 4;
    int px   = pxb + pr;
    int h = px >> 7, w = px & (W_ - 1);
    const _Float16* xb = xT + (((size_t)b << 14) << 6);

    f32x4 acc[2];
#pragma unroll
    for (int nb = 0; nb < 2; ++nb) acc[nb] = (f32x4){0.f, 0.f, 0.f, 0.f};

    u32x4 q[3][2];
    bool  vld[3];

    auto issueO = [&](int kk, int st) {
        int ky = kk / 3, kx = kk % 3;
        int yy = h - 1 + ky, xx = w - 1 + kx;
        vld[st] = ((unsigned)yy < (unsigned)H_) && ((unsigned)xx < (unsigned)W_);
        int src = (min(max(yy, 0), H_ - 1) << 7) + min(max(xx, 0), W_ - 1);
        unsigned long long a = (unsigned long long)(xb + ((size_t)src << 6) + g * 8);
        GLOAD16(q[st][0], a);
        unsigned long long a2 = a + 64;
        GLOAD16(q[st][1], a2);
    };

    issueO(0, 0); issueO(1, 1); issueO(2, 2);
#pragma unroll
    for (int kk = 0; kk < KK_; ++kk) {
        const int s = kk % 3;
        if (kk < 7)      { WAITV(4); }
        else if (kk < 8) { WAITV(2); }
        else             { WAITV(0); }
#pragma unroll
        for (int kc = 0; kc < 2; ++kc) {
            f16x8 a = u2h8(q[s][kc]);
            f16x8 z = {};
            a = vld[s] ? a : z;
#pragma unroll
            for (int nb = 0; nb < 2; ++nb) {
                f16x8 bfr = *(const f16x8*)(wlds +
                    ((((kk * 2 + kc) << 1) + nb) << 9) + (lane << 3));
                acc[nb] = __builtin_amdgcn_mfma_f32_16x16x32_f16(a, bfr, acc[nb], 0, 0, 0);
            }
        }
        if (kk < 6) issueO(kk + 3, s);
    }

#pragma unroll
    for (int nb = 0; nb < 2; ++nb) {
        int m = nb * 16 + pr;
        if (m < NOFF_) {
            float bias = b_off[m];
#pragma unroll
            for (int r = 0; r < 4; ++r) {
                int prow = pxb + g * 4 + r;
                offsh[(size_t)((b << 14) + prow) * NOFF_ + m] = (_Float16)(acc[nb][r] + bias);
            }
        }
    }
}

// ---------------------------------------------------------------------------
// Deformable conv R13: BRANCH-FREE main loop. Always-safe clamped LDS reads
// (bad lanes recorded in a 9-bit mask), q/weights double-buffered with named
// regs, tie-waited weights — the only asm in the loop. Rare bad samples are
// repaired AFTER the loop by MFMA-ing the (exact - wrong) fragment diff
// (MFMA is linear; diff zeroed on good lanes).
// ---------------------------------------------------------------------------
__global__ __launch_bounds__(256, 2) void deform_mfma12(
    const _Float16* __restrict__ xT, const _Float16* __restrict__ offsh,
    const _Float16* __restrict__ wfrag, float* __restrict__ out)
{
    __shared__ char tilec[TW_ * TW_ * RSTR_];   // 51,984 B

    int t    = threadIdx.x;
    int blk  = blockIdx.x;
    int b    = blk & 7;                       // XCD-aligned batch
    int tid  = blk >> 3;                      // 0..255 tile id
    int ty   = tid >> 4, tx = tid & 15;
    int lane = t & 63;
    int wv   = t >> 6;
    int pr   = lane & 15;                     // fragment px row
    int gg   = lane >> 4;                     // fragment k-group
    int ry0  = ty * 8 - PADW_;
    int cx0  = tx * 8 - PADW_;
    const _Float16* xb = xT + (((size_t)b << 14) << 6);

    // ---- stage clamped 19x19 neighborhood (coalesced, stride-144 rows) ----
#pragma unroll
    for (int it = 0; it < 12; ++it) {
        int idx = it * 256 + t;
        if (idx < TW_ * TW_ * 8) {
            int i   = idx / (TW_ * 8);
            int rem = idx - i * (TW_ * 8);
            int j   = rem >> 3, cg = rem & 7;
            int yy = min(max(ry0 + i, 0), H_ - 1);
            int xx = min(max(cx0 + j, 0), W_ - 1);
            u32x4 v = *(const u32x4*)(xb + (((size_t)((yy << 7) + xx)) << 6) + (cg << 3));
            int rl = i * TW_ + j;
            *(u32x4*)(tilec + rl * RSTR_ + (cg << 4)) = v;
        }
    }

    int h_img = ty * 8 + wv * 2 + (pr >> 3);
    int w_img = tx * 8 + (pr & 7);
    const uint32* obu = (const uint32*)(offsh +
        (size_t)((b << 14) + (h_img << 7) + w_img) * NOFF_);
    uint32 dpk[9];
#pragma unroll
    for (int kk = 0; kk < 9; ++kk) dpk[kk] = obu[kk];
    DRAIN_ALL();
    __syncthreads();

    f32x4 acc[4];
#pragma unroll
    for (int nb = 0; nb < 4; ++nb) acc[nb] = (f32x4){0.f, 0.f, 0.f, 0.f};

    // bilinear prep: corner weights, clamped LDS row-ids, exact corner coords
    auto prepk = [&](int kk, f16x2* Wc, int* rlc, int* ycx) -> int {
        int ky = kk / 3, kx = kk % 3;
        union { uint32 u; f16x2 hh; } cv; cv.u = dpk[kk];
        float dyv = (float)cv.hh[0], dxv = (float)cv.hh[1];
        float py  = (float)(h_img - 1 + ky) + dyv;
        float pxf = (float)(w_img - 1 + kx) + dxv;
        float y0f = floorf(py), x0f = floorf(pxf);
        float ly = py - y0f, lx = pxf - x0f;
        int y0 = (int)y0f, x0 = (int)x0f;
        float w00 = (1.f - ly) * (1.f - lx);
        float w01 = (1.f - ly) * lx;
        float w10 = ly * (1.f - lx);
        float w11 = ly * lx;
        bool vy0 = (unsigned)y0       < (unsigned)H_;
        bool vy1 = (unsigned)(y0 + 1) < (unsigned)H_;
        bool vx0 = (unsigned)x0       < (unsigned)W_;
        bool vx1 = (unsigned)(x0 + 1) < (unsigned)W_;
        if (!(vy0 && vx0)) w00 = 0.f;
        if (!(vy0 && vx1)) w01 = 0.f;
        if (!(vy1 && vx0)) w10 = 0.f;
        if (!(vy1 && vx1)) w11 = 0.f;
        int yc0 = min(max(y0, 0), H_ - 1);
        int yc1 = min(max(y0 + 1, 0), H_ - 1);
        int xc0 = min(max(x0, 0), W_ - 1);
        int xc1 = min(max(x0 + 1, 0), W_ - 1);
        Wc[0] = (f16x2){(_Float16)w00, (_Float16)w00};
        Wc[1] = (f16x2){(_Float16)w01, (_Float16)w01};
        Wc[2] = (f16x2){(_Float16)w10, (_Float16)w10};
        Wc[3] = (f16x2){(_Float16)w11, (_Float16)w11};
        ycx[0] = yc0; ycx[1] = yc1; ycx[2] = xc0; ycx[3] = xc1;
        int r0 = yc0 - ry0, r1 = yc1 - ry0;
        int c0 = xc0 - cx0, c1 = xc1 - cx0;
        int bad = ((unsigned)r0 >= TW_) | ((unsigned)r1 >= TW_) |
                  ((unsigned)c0 >= TW_) | ((unsigned)c1 >= TW_);
        // clamp to window for always-safe LDS addressing
        r0 = min(max(r0, 0), TW_ - 1); r1 = min(max(r1, 0), TW_ - 1);
        c0 = min(max(c0, 0), TW_ - 1); c1 = min(max(c1, 0), TW_ - 1);
        rlc[0] = r0 * TW_ + c0; rlc[1] = r0 * TW_ + c1;
        rlc[2] = r1 * TW_ + c0; rlc[3] = r1 * TW_ + c1;
        return bad;
    };
    auto ldsRead = [&](const int* rlc, u32x4* q) {
#pragma unroll
        for (int kc = 0; kc < 2; ++kc) {
            int ch = (gg << 4) + (kc << 6);
#pragma unroll
            for (int cr = 0; cr < 4; ++cr)
                q[kc * 4 + cr] = *(const u32x4*)(tilec + rlc[cr] * RSTR_ + ch);
        }
    };
    auto issueW = [&](int kk, u32x4* wq) {
#pragma unroll
        for (int f = 0; f < 8; ++f) {
            unsigned long long wa = (unsigned long long)(wfrag +
                ((((kk * 2 + (f >> 2)) << 2) + (f & 3)) << 9) + (lane << 3));
            GLOAD16(wq[f], wa);
        }
    };
    auto bilerp = [&](const u32x4* q, const f16x2* Wc, int kc) -> f16x8 {
        f16x8 a;
        f16x2* ap = (f16x2*)&a;
#pragma unroll
        for (int p4 = 0; p4 < 4; ++p4) {
            ap[p4] = u2h(q[kc * 4 + 0][p4]) * Wc[0]
                   + u2h(q[kc * 4 + 1][p4]) * Wc[1]
                   + u2h(q[kc * 4 + 2][p4]) * Wc[2]
                   + u2h(q[kc * 4 + 3][p4]) * Wc[3];
        }
        return a;
    };

    u32x4 qA[8], qB[8], wqA[8], wqB[8];
    f16x2 WcA[4], WcB[4];
    int   rlA[4], rlB[4], ycxT[4];
    uint32 badmask = 0;

    issueW(0, wqA);
    if (prepk(0, WcA, rlA, ycxT)) badmask |= 1u;
    ldsRead(rlA, qA);

#pragma unroll
    for (int kk = 0; kk < KK_; ++kk) {
        u32x4* wcur = (kk & 1) ? wqB : wqA;
        u32x4* wnxt = (kk & 1) ? wqA : wqB;
        u32x4* qcur = (kk & 1) ? qB : qA;
        u32x4* qnxt = (kk & 1) ? qA : qB;
        f16x2* Wcur = (kk & 1) ? WcB : WcA;
        f16x2* Wnxt = (kk & 1) ? WcA : WcB;
        int*   rlnx = (kk & 1) ? rlA : rlB;

        if (kk < 8) {
            issueW(kk + 1, wnxt);
            if (prepk(kk + 1, Wnxt, rlnx, ycxT)) badmask |= (1u << (kk + 1));
            ldsRead(rlnx, qnxt);
        }

        f16x8 a0 = bilerp(qcur, Wcur, 0);
        f16x8 a1 = bilerp(qcur, Wcur, 1);

        if (kk < 8) { WAITV_TIE(8, wcur); } else { WAITV_TIE(0, wcur); }

#pragma unroll
        for (int nb = 0; nb < 4; ++nb)
            acc[nb] = __builtin_amdgcn_mfma_f32_16x16x32_f16(a0, u2h8(wcur[nb]), acc[nb], 0, 0, 0);
#pragma unroll
        for (int nb = 0; nb < 4; ++nb)
            acc[nb] = __builtin_amdgcn_mfma_f32_16x16x32_f16(a1, u2h8(wcur[4 + nb]), acc[nb], 0, 0, 0);
    }

    // ---- rare exact fix-up: acc += W * (exact - wrong), zero on good lanes --
    if (__any((int)(badmask != 0))) {
#pragma unroll 1
        for (int kk = 0; kk < KK_; ++kk) {
            int mybad = (badmask >> kk) & 1;
            if (__any(mybad)) {
                f16x2 Wc[4]; int rlc[4], ycx[4];
                prepk(kk, Wc, rlc, ycx);
                u32x4 qw[8], qr[8];
                ldsRead(rlc, qw);                       // wrong (as main loop)
#pragma unroll
                for (int kc = 0; kc < 2; ++kc) {
                    int ce = ((kc << 2) + gg) << 3;
#pragma unroll
                    for (int cr = 0; cr < 4; ++cr) {
                        int yy = ycx[cr >> 1], xx = ycx[2 + (cr & 1)];
                        unsigned long long a = (unsigned long long)(xb +
                            (((size_t)((yy << 7) + xx)) << 6) + ce);
                        GLOAD16(qr[kc * 4 + cr], a);    // exact
                    }
                }
                issueW(kk, wqA);
                WAITV(0);
#pragma unroll
                for (int kc = 0; kc < 2; ++kc) {
                    f16x8 aw = bilerp(qw, Wc, kc);
                    f16x8 ar = bilerp(qr, Wc, kc);
                    f16x8 d  = ar - aw;
                    f16x8 z  = {};
                    d = mybad ? d : z;
#pragma unroll
                    for (int nb = 0; nb < 4; ++nb)
                        acc[nb] = __builtin_amdgcn_mfma_f32_16x16x32_f16(
                            d, u2h8(wqA[kc * 4 + nb]), acc[nb], 0, 0, 0);
                }
            }
        }
    }

    // C/D: col=lane&15 -> o; row=gg*4+r -> p_local -> (row pair, col quad)
#pragma unroll
    for (int nb = 0; nb < 4; ++nb) {
        int o = nb * 16 + pr;
        int orow = ty * 8 + wv * 2 + (gg >> 1);
        int ocol = tx * 8 + ((gg & 1) << 2);
        float* outp = out + (((size_t)(b * O_ + o)) << 14) + (orow << 7) + ocol;
        *(f32x4*)outp = acc[nb];
    }
}

// ===========================================================================
extern "C" void kernel_launch(void* const* d_in, const int* in_sizes, int n_in,
                              void* d_out, int out_size, void* d_ws, size_t ws_size,
                              hipStream_t stream)
{
    const float* x      = (const float*)d_in[0];
    const float* w_off  = (const float*)d_in[1];
    const float* b_off  = (const float*)d_in[2];
    const float* w_conv = (const float*)d_in[3];
    float* out = (float*)d_out;
    char* ws = (char*)d_ws;

    // workspace layout (bytes) — total 21,643,264
    const size_t XT_OFF    = 0;           // 16,777,216  f16 NHWC x
    const size_t OFFS_OFF  = 16777216;    //  4,718,592  f16 NHWC offsets
    const size_t WFRAG_OFF = 21495808;    //     73,728  deform weight frags
    const size_t WOFF_OFF  = 21569536;    //     36,864  offset weight frags

    _Float16* xT    = (_Float16*)(ws + XT_OFF);
    _Float16* offsh = (_Float16*)(ws + OFFS_OFF);
    _Float16* wfrag = (_Float16*)(ws + WFRAG_OFF);
    _Float16* wofff = (_Float16*)(ws + WOFF_OFF);

    transpose_x  <<<2048, 256, 0, stream>>>(x, xT);
    prep3        <<<144, 256, 0, stream>>>(w_conv, w_off, wfrag, wofff);
    offconv_mfma5<<<1024, 512, 0, stream>>>(xT, wofff, b_off, offsh);
    deform_mfma12<<<2048, 256, 0, stream>>>(xT, offsh, wfrag, out);
}